// Round 1
// baseline (39.378 us; speedup 1.0000x reference)
//
#include <hip/hip_runtime.h>

// x: [B=8, C=3, T=32, H=224, W=224] float32.
// out[b,c,t,h,w] = (w - tx[t] >= 0) ? x[b,c,t,h, w - tx[t]] : 0
// tx[t] = trunc(0.08 * |t - T/2| * W) = (2240 * dist) / 125  (exact integer form)

#define TT 32
#define HH 224
#define WW 224
#define W4 56   // WW / 4

__global__ __launch_bounds__(256) void shift_kernel(const float* __restrict__ in,
                                                    float* __restrict__ out,
                                                    int nvec /* total float4s */) {
    const int stride = gridDim.x * blockDim.x;
    for (int v = blockIdx.x * blockDim.x + threadIdx.x; v < nvec; v += stride) {
        int w4  = v % W4;          // float4 index within row
        int row = v / W4;          // global row index over B*C*T*H
        int t   = (row / HH) % TT; // frame index

        int dist = t - 16; if (dist < 0) dist = -dist;
        int tx   = (2240 * dist) / 125;   // exact trunc(17.92 * dist)

        float4 o;
        if (tx >= WW) {
            o.x = 0.f; o.y = 0.f; o.z = 0.f; o.w = 0.f;
        } else {
            const float* __restrict__ rowp = in + (size_t)row * WW;
            int s = w4 * 4 - tx;   // source column of first element
            o.x = (s + 0 >= 0) ? rowp[s + 0] : 0.f;
            o.y = (s + 1 >= 0) ? rowp[s + 1] : 0.f;
            o.z = (s + 2 >= 0) ? rowp[s + 2] : 0.f;
            o.w = (s + 3 >= 0) ? rowp[s + 3] : 0.f;
        }
        reinterpret_cast<float4*>(out)[v] = o;
    }
}

extern "C" void kernel_launch(void* const* d_in, const int* in_sizes, int n_in,
                              void* d_out, int out_size, void* d_ws, size_t ws_size,
                              hipStream_t stream) {
    const float* x = (const float*)d_in[0];
    float* out = (float*)d_out;

    const int nvec = out_size / 4;   // 38,535,168 / 4 = 9,633,792
    int blocks = (nvec + 255) / 256;
    if (blocks > 2048) blocks = 2048;

    shift_kernel<<<blocks, 256, 0, stream>>>(x, out, nvec);
}